// Round 1
// 61.782 us; speedup vs baseline: 1.0903x; 1.0903x over previous
//
#include <hip/hip_runtime.h>
#include <cmath>

#define DEVFN __device__ __forceinline__

constexpr int Bn = 4096, Dn = 1024, An = 64, Tn = 16;
constexpr int CAP = 512;     // per-task row capacity (mean 256, +16.5 sigma)

// ---------------- workspace layout (bytes) ----------------
constexpr size_t OFF_CURSOR = 0;                                 // Tn ints
constexpr size_t OFF_BUCKET = 256;                               // Tn*CAP ints = 32KB
constexpr size_t OFF_FEATB  = 33024;                             // bf16 [Bn][Dn] = 8MB
constexpr size_t OFF_H      = OFF_FEATB + (size_t)2 * Bn * Dn;   // bf16 [Tn*CAP][Dn] = 16MB
constexpr size_t WS_NEED    = OFF_H + (size_t)2 * Tn * CAP * Dn; // ~25.2MB

typedef unsigned short u16;
typedef unsigned int uint32;
typedef __bf16 bf16x8 __attribute__((ext_vector_type(8)));
typedef float f32x4 __attribute__((ext_vector_type(4)));

DEVFN u16 f2b(float x) {            // f32 -> bf16 RNE
    unsigned u = __float_as_uint(x);
    u = u + 0x7FFFu + ((u >> 16) & 1u);
    return (u16)(u >> 16);
}
DEVFN uint32 pk2(float lo, float hi) {   // packed f32x2 -> bf16x2 (RNE)
    uint32 r;
    asm("v_cvt_pk_bf16_f32 %0, %1, %2" : "=v"(r) : "v"(lo), "v"(hi));
    return r;
}
DEVFN void gload_lds16(const void* g, void* l) {
    __builtin_amdgcn_global_load_lds(
        (const __attribute__((address_space(1))) void*)g,
        (__attribute__((address_space(3))) void*)l, 16, 0, 0);
}

// ---------------- prep: feature cvt + cursor zero (W1 path now fused in gemm1)
__global__ __launch_bounds__(256) void k_prep(
    const float* __restrict__ feat, u16* __restrict__ featb, int* __restrict__ cursor) {
    const int bid = blockIdx.x, tid = threadIdx.x;
    if (bid == 0 && tid < Tn) cursor[tid] = 0;      // nothing reads cursor in this kernel
    const float4* s = (const float4*)feat;
    ushort4* d = (ushort4*)featb;
    const int base = bid * 1024 + tid;
    #pragma unroll
    for (int i = 0; i < 4; ++i) {
        float4 v = s[base + i * 256];
        ushort4 o = {f2b(v.x), f2b(v.y), f2b(v.z), f2b(v.w)};
        d[base + i * 256] = o;
    }
}

// ---------------- scatter: argmax + bucket append (CAP segments) -------------
__global__ void k_scatter(const float* __restrict__ ai, int* __restrict__ cursor,
                          int* __restrict__ bucket) {
    int b = blockIdx.x * 256 + threadIdx.x;
    if (b >= Bn) return;
    const float4* r = (const float4*)(ai + (size_t)b * Tn);
    float4 v0 = r[0], v1 = r[1], v2 = r[2], v3 = r[3];
    float vals[16] = {v0.x, v0.y, v0.z, v0.w, v1.x, v1.y, v1.z, v1.w,
                      v2.x, v2.y, v2.z, v2.w, v3.x, v3.y, v3.z, v3.w};
    float best = vals[0]; int bi = 0;
    #pragma unroll
    for (int i = 1; i < Tn; ++i) if (vals[i] > best) { best = vals[i]; bi = i; }
    int pos = atomicAdd(&cursor[bi], 1);
    if (pos < CAP) bucket[bi * CAP + pos] = b;
}

// ---------------- gemm1: h = relu(feat @ W1[t] + b1[t]), W1 read as f32 -----
// BM=128, BN=128, BK=64; 512 thr = 8 waves. Wave-specialized staging:
//   waves 0-3 (B): reg-stage W1 f32 (8x global_load_dwordx4, coalesced 512B
//     runs) -> v_cvt_pk_bf16_f32 -> 4x ds_write_b128 (in-register k-transpose).
//   waves 4-7 (A): global_load_lds of gathered featb rows (linear dest +
//     inverse-swizzled source, rule #21), 4 per thread.
// Depth-1 pipeline: issue loads(ks+1) at iter top; consume after the 16-MFMA
// compute phase (latency window = compute; 2 blocks/CU adds overlap).
//   B-waves: pk2 auto-waits loads; lgkmcnt(0) publishes ds_writes pre-barrier.
//   A-waves: vmcnt(0) retires gload_lds DMA pre-barrier (no reg consumer).
// B swizzle: chunk idx = kc ^ (n&7) ^ ((n>>3)&7). Write phase (n=4*(lane&31)+j,
// kc uniform): slots j^{0..7} distinct. Read phase (n=base+lane&15): {0..7}^v
// distinct. Both conflict-free; A keeps old kc^(row&7) scheme.
__global__ __launch_bounds__(512, 4) void k_gemm1(
    const u16* __restrict__ featb, const float* __restrict__ w1,
    const float* __restrict__ b1, const int* __restrict__ bucket,
    const int* __restrict__ cursor, u16* __restrict__ hbuf) {
    __shared__ __align__(16) u16 As[2][128 * 64];   // 16KB x2
    __shared__ __align__(16) u16 Bs[2][128 * 64];   // 16KB x2  (64KB total)
    __shared__ int ri[128];

    const int bid = blockIdx.x;                     // t fastest -> XCD pin
    const int t = bid & 15, nt = (bid >> 4) & 7, mt = bid >> 7;   // mt 0..3
    int cnt = cursor[t]; if (cnt > CAP) cnt = CAP;
    const int m0 = mt * 128;
    if (m0 >= cnt) return;
    const int n0 = nt * 128;
    const int tid = threadIdx.x, lane = tid & 63, wv = tid >> 6;
    const int wr = wv >> 2, wc = wv & 3;            // 2 x 4 wave grid, tile 64x32
    const bool isB = (wv < 4);

    if (tid < 128) { int r = m0 + tid; ri[tid] = bucket[t * CAP + (r < cnt ? r : cnt - 1)]; }
    __syncthreads();

    // B stager: kc = k-octet 0..7, nq = n-quad 0..31 (n = nq*4 + nn)
    const int kc = (tid >> 5) & 7, nq = tid & 31;
    const float* pw = w1 + ((size_t)t * Dn + kc * 8) * Dn + n0 + nq * 4;
    int boff[4];
    #pragma unroll
    for (int nn = 0; nn < 4; ++nn) {
        const int n = nq * 4 + nn;
        boff[nn] = n * 64 + 8 * (kc ^ (n & 7) ^ ((n >> 3) & 7));
    }
    f32x4 regB[8];

    // A stager: chunk g = i*256 + (tid-256) -> row g>>3, k-slot g&7
    const u16* pa[4];
    if (!isB) {
        #pragma unroll
        for (int i = 0; i < 4; ++i) {
            const int g = i * 256 + (tid - 256);
            const int row = g >> 3, kca = g & 7;
            pa[i] = featb + (size_t)ri[row] * Dn + 8 * (kca ^ (row & 7));
        }
    }

    auto loadB = [&](int ks) {
        const float* p = pw + (size_t)ks * 64 * Dn;
        #pragma unroll
        for (int kk = 0; kk < 8; ++kk) regB[kk] = *(const f32x4*)(p + (size_t)kk * Dn);
    };
    auto writeB = [&](int buf) {
        #pragma unroll
        for (int nn = 0; nn < 4; ++nn) {
            uint4 w = {pk2(regB[0][nn], regB[1][nn]), pk2(regB[2][nn], regB[3][nn]),
                       pk2(regB[4][nn], regB[5][nn]), pk2(regB[6][nn], regB[7][nn])};
            *(uint4*)&Bs[buf][boff[nn]] = w;
        }
    };
    auto loadA = [&](int ks, int buf) {
        #pragma unroll
        for (int i = 0; i < 4; ++i)
            gload_lds16(pa[i] + ks * 64, &As[buf][(i * 256 + (tid - 256)) * 8]);
    };

    f32x4 acc[4][2] = {};
    if (isB) { loadB(0); writeB(0); } else { loadA(0, 0); }
    asm volatile("s_waitcnt vmcnt(0) lgkmcnt(0)\n\ts_barrier" ::: "memory");

    for (int ks = 0; ks < 16; ++ks) {
        const int cur = ks & 1;
        if (ks < 15) { if (isB) loadB(ks + 1); else loadA(ks + 1, cur ^ 1); }

        #pragma unroll
        for (int h = 0; h < 2; ++h) {
            const int kq = h * 4 + (lane >> 4);
            bf16x8 af[4], bfr[2];
            #pragma unroll
            for (int i = 0; i < 4; ++i) {
                int rr = wr * 64 + i * 16 + (lane & 15);
                af[i] = *(const bf16x8*)&As[cur][rr * 64 + 8 * (kq ^ (rr & 7))];
            }
            #pragma unroll
            for (int j = 0; j < 2; ++j) {
                int nn = wc * 32 + j * 16 + (lane & 15);
                bfr[j] = *(const bf16x8*)&Bs[cur][nn * 64 + 8 * (kq ^ (nn & 7) ^ ((nn >> 3) & 7))];
            }
            #pragma unroll
            for (int i = 0; i < 4; ++i)
                #pragma unroll
                for (int j = 0; j < 2; ++j)
                    acc[i][j] = __builtin_amdgcn_mfma_f32_16x16x32_bf16(af[i], bfr[j], acc[i][j], 0, 0, 0);
        }

        if (ks < 15) {
            if (isB) {
                writeB(cur ^ 1);    // tile ks+1 -> buf^1 (read next iter)
                asm volatile("s_waitcnt lgkmcnt(0)" ::: "memory");
            } else {
                asm volatile("s_waitcnt vmcnt(0)" ::: "memory");
            }
        }
        // bare barrier: publishes buf^1 staging; protects cur from next iter's
        // staging (all reads of cur were consumed by MFMAs above).
        asm volatile("s_barrier" ::: "memory");
    }

    #pragma unroll
    for (int j = 0; j < 2; ++j) {
        const int n = n0 + wc * 32 + j * 16 + (lane & 15);
        const float bias = b1[t * Dn + n];
        #pragma unroll
        for (int i = 0; i < 4; ++i) {
            #pragma unroll
            for (int r = 0; r < 4; ++r) {
                const int row = wr * 64 + i * 16 + (lane >> 4) * 4 + r;
                if (m0 + row < cnt) {
                    float v = acc[i][j][r] + bias;
                    v = v > 0.f ? v : 0.f;
                    hbuf[(size_t)(t * CAP + m0 + row) * Dn + n] = f2b(v);
                }
            }
        }
    }
}

// ---------------- gemm2 fused-K + epilogue (tanh, std, scatter) --------------
__global__ __launch_bounds__(256, 3) void k_gemm2(
    const u16* __restrict__ hbuf, const float* __restrict__ w2,
    const float* __restrict__ b2, const float* __restrict__ sigma,
    const int* __restrict__ cursor, const int* __restrict__ bucket,
    float* __restrict__ out) {
    __shared__ __align__(16) u16 Asl[32 * 256];   // 16KB [row][k] swizzled
    __shared__ __align__(16) u16 Bsl[64 * 256];   // 32KB [a][k]  swizzled

    const int bid = blockIdx.x;
    const int t = bid & 15, mt = bid >> 4;        // mt 0..15 (32-row tiles)
    int cnt = cursor[t]; if (cnt > CAP) cnt = CAP;
    const int m0 = mt * 32;
    if (m0 >= cnt) return;
    const int tid = threadIdx.x, lane = tid & 63, wv = tid >> 6;
    const int rh = wv & 1, ag = wv >> 1;

    f32x4 acc[2] = {};
    for (int c = 0; c < 4; ++c) {
        const int k0 = c * 256;
        #pragma unroll
        for (int i = 0; i < 4; ++i) {
            int chunk = i * 256 + tid;
            int row = chunk >> 5, cp = chunk & 31;
            int rowg = m0 + row; if (rowg >= cnt) rowg = cnt - 1;
            gload_lds16(hbuf + (size_t)(t * CAP + rowg) * Dn + k0 + 8 * (cp ^ (row & 7)),
                        &Asl[chunk * 8]);
        }
        {
            const int a = tid & 63, kcq = tid >> 6;
            const float* gB = w2 + ((size_t)t * Dn + k0 + kcq * 64) * An + a;
            for (int jb = 0; jb < 8; ++jb) {
                float v[8];
                #pragma unroll
                for (int u = 0; u < 8; ++u) v[u] = gB[(size_t)(jb * 8 + u) * An];
                int k = kcq * 64 + jb * 8;
                uint4 w = {pk2(v[0], v[1]), pk2(v[2], v[3]), pk2(v[4], v[5]), pk2(v[6], v[7])};
                *(uint4*)&Bsl[a * 256 + 8 * ((k >> 3) ^ (a & 7))] = w;
            }
        }
        __syncthreads();
        #pragma unroll
        for (int s = 0; s < 8; ++s) {
            const int r = lane & 15, ch = lane >> 4, cp = s * 4 + ch;
            const int row = rh * 16 + r;
            bf16x8 af = *(const bf16x8*)&Asl[row * 256 + 8 * (cp ^ (row & 7))];
            #pragma unroll
            for (int j = 0; j < 2; ++j) {
                const int a = ag * 32 + j * 16 + r;
                bf16x8 bf = *(const bf16x8*)&Bsl[a * 256 + 8 * (cp ^ (a & 7))];
                acc[j] = __builtin_amdgcn_mfma_f32_16x16x32_bf16(af, bf, acc[j], 0, 0, 0);
            }
        }
        __syncthreads();
    }

    #pragma unroll
    for (int j = 0; j < 2; ++j) {
        const int a = ag * 32 + j * 16 + (lane & 15);
        const float bias = b2[t * An + a];
        const float sd = expf(sigma[t * An + a]);
        #pragma unroll
        for (int r = 0; r < 4; ++r) {
            const int row = m0 + rh * 16 + (lane >> 4) * 4 + r;
            if (row < cnt) {
                const int orig = bucket[t * CAP + row];
                out[(size_t)orig * An + a] = tanhf(acc[j][r] + bias);
                out[(size_t)Bn * An + (size_t)orig * An + a] = sd;
            }
        }
    }
}

// ---------------- launch: 4 nodes, no memset ----------------
extern "C" void kernel_launch(void* const* d_in, const int* in_sizes, int n_in,
                              void* d_out, int out_size, void* d_ws, size_t ws_size,
                              hipStream_t stream) {
    const float* feature = (const float*)d_in[0];
    const float* actor_index = (const float*)d_in[1];
    const float* W1 = (const float*)d_in[2];
    const float* b1 = (const float*)d_in[3];
    const float* W2 = (const float*)d_in[4];
    const float* b2 = (const float*)d_in[5];
    const float* sigma = (const float*)d_in[6];
    float* out = (float*)d_out;
    char* ws = (char*)d_ws;

    if (ws_size < WS_NEED) return;

    int* cursor = (int*)(ws + OFF_CURSOR);
    int* bucket = (int*)(ws + OFF_BUCKET);
    u16* featb  = (u16*)(ws + OFF_FEATB);
    u16* hbuf   = (u16*)(ws + OFF_H);

    k_prep<<<1024, 256, 0, stream>>>(feature, featb, cursor);
    k_scatter<<<Bn / 256, 256, 0, stream>>>(actor_index, cursor, bucket);
    k_gemm1<<<Tn * 8 * 4, 512, 0, stream>>>(featb, W1, b1, bucket, cursor, hbuf);
    k_gemm2<<<Tn * 16, 256, 0, stream>>>(hbuf, W2, b2, sigma, cursor, bucket, out);
}

// Round 2
// 59.776 us; speedup vs baseline: 1.1269x; 1.0336x over previous
//
#include <hip/hip_runtime.h>
#include <cmath>

#define DEVFN __device__ __forceinline__

constexpr int Bn = 4096, Dn = 1024, An = 64, Tn = 16;
constexpr int CAP = 512;     // per-task row capacity (mean 256, +16.5 sigma)

// ---------------- workspace layout (bytes) ----------------
constexpr size_t OFF_CURSOR = 0;                                 // Tn ints
constexpr size_t OFF_BUCKET = 256;                               // Tn*CAP ints = 32KB
constexpr size_t OFF_FEATB  = 33024;                             // bf16 [Bn][Dn] = 8MB
constexpr size_t OFF_H      = OFF_FEATB + (size_t)2 * Bn * Dn;   // bf16 [Tn*CAP][Dn] = 16MB
constexpr size_t WS_NEED    = OFF_H + (size_t)2 * Tn * CAP * Dn; // ~25.2MB

typedef unsigned short u16;
typedef unsigned int uint32;
typedef __bf16 bf16x8 __attribute__((ext_vector_type(8)));
typedef float f32x4 __attribute__((ext_vector_type(4)));

DEVFN u16 f2b(float x) {            // f32 -> bf16 RNE
    unsigned u = __float_as_uint(x);
    u = u + 0x7FFFu + ((u >> 16) & 1u);
    return (u16)(u >> 16);
}
DEVFN uint32 pk2(float lo, float hi) {   // packed f32x2 -> bf16x2 (RNE)
    uint32 r;
    asm("v_cvt_pk_bf16_f32 %0, %1, %2" : "=v"(r) : "v"(lo), "v"(hi));
    return r;
}
DEVFN void gload_lds16(const void* g, void* l) {
    __builtin_amdgcn_global_load_lds(
        (const __attribute__((address_space(1))) void*)g,
        (__attribute__((address_space(3))) void*)l, 16, 0, 0);
}

// ---------------- prep: feature cvt + cursor zero ----------------------------
__global__ __launch_bounds__(256) void k_prep(
    const float* __restrict__ feat, u16* __restrict__ featb, int* __restrict__ cursor) {
    const int bid = blockIdx.x, tid = threadIdx.x;
    if (bid == 0 && tid < Tn) cursor[tid] = 0;      // nothing reads cursor in this kernel
    const float4* s = (const float4*)feat;
    ushort4* d = (ushort4*)featb;
    const int base = bid * 1024 + tid;
    #pragma unroll
    for (int i = 0; i < 4; ++i) {
        float4 v = s[base + i * 256];
        ushort4 o = {f2b(v.x), f2b(v.y), f2b(v.z), f2b(v.w)};
        d[base + i * 256] = o;
    }
}

// ---------------- scatter: argmax + bucket append (CAP segments) -------------
__global__ void k_scatter(const float* __restrict__ ai, int* __restrict__ cursor,
                          int* __restrict__ bucket) {
    int b = blockIdx.x * 256 + threadIdx.x;
    if (b >= Bn) return;
    const float4* r = (const float4*)(ai + (size_t)b * Tn);
    float4 v0 = r[0], v1 = r[1], v2 = r[2], v3 = r[3];
    float vals[16] = {v0.x, v0.y, v0.z, v0.w, v1.x, v1.y, v1.z, v1.w,
                      v2.x, v2.y, v2.z, v2.w, v3.x, v3.y, v3.z, v3.w};
    float best = vals[0]; int bi = 0;
    #pragma unroll
    for (int i = 1; i < Tn; ++i) if (vals[i] > best) { best = vals[i]; bi = i; }
    int pos = atomicAdd(&cursor[bi], 1);
    if (pos < CAP) bucket[bi * CAP + pos] = b;
}

// ---------------- gemm1: h = relu(feat @ W1[t] + b1[t]), W1 read as f32 -----
// BM=128, BN=128, BK=64; 512 thr = 8 waves. Wave-specialized staging with
// FULL-ITERATION prefetch distance (wait-before-compute, counted):
//   iter ks (compute tile ks from buf p=ks&1):
//   (a) B-waves: writeB(p^1) from regB holding tile ks+1 (loaded at iter ks-1
//         -> pk2's implied vmcnt finds data landed); then reload the SAME regB
//         set with tile ks+2 (WAR reuse keeps it at 32 VGPRs).
//       A-waves: issue 4x global_load_lds for tile ks+1 -> As[p^1].
//   (b) A-waves: s_waitcnt vmcnt(4)  -- retires exactly tile ks's DMA (oldest
//         4 of 8 outstanding); tile ks+1 rides through the barrier.
//       B-waves: s_waitcnt lgkmcnt(0) -- publish ds_writes of (a).
//       s_barrier; compute(p); bare s_barrier (protects p from next iter's
//       staging; compiler's lgkm waits before MFMAs retired all p reads).
// The asm-"memory" at (b) sits BETWEEN load-issue and compute, so the compiler
// cannot sink the W1 loads into writeB (the round-1 bug: VGPR=56 proved regB
// was never live across compute -> zero prefetch -> latency-serial K-steps).
// B swizzle: chunk idx = kc ^ (n&7) ^ ((n>>3)&7) (write & read conflict-free).
__global__ __launch_bounds__(512, 4) void k_gemm1(
    const u16* __restrict__ featb, const float* __restrict__ w1,
    const float* __restrict__ b1, const int* __restrict__ bucket,
    const int* __restrict__ cursor, u16* __restrict__ hbuf) {
    __shared__ __align__(16) u16 As[2][128 * 64];   // 16KB x2
    __shared__ __align__(16) u16 Bs[2][128 * 64];   // 16KB x2  (64KB total)
    __shared__ int ri[128];

    const int bid = blockIdx.x;                     // t fastest -> XCD pin
    const int t = bid & 15, nt = (bid >> 4) & 7, mt = bid >> 7;   // mt 0..3
    int cnt = cursor[t]; if (cnt > CAP) cnt = CAP;
    const int m0 = mt * 128;
    if (m0 >= cnt) return;
    const int n0 = nt * 128;
    const int tid = threadIdx.x, lane = tid & 63, wv = tid >> 6;
    const int wr = wv >> 2, wc = wv & 3;            // 2 x 4 wave grid, tile 64x32
    const bool isB = (wv < 4);

    if (tid < 128) { int r = m0 + tid; ri[tid] = bucket[t * CAP + (r < cnt ? r : cnt - 1)]; }
    __syncthreads();

    // B stager: kc = k-octet 0..7, nq = n-quad 0..31 (n = nq*4 + nn)
    const int kc = (tid >> 5) & 7, nq = tid & 31;
    const float* pw = w1 + ((size_t)t * Dn + kc * 8) * Dn + n0 + nq * 4;
    int boff[4];
    #pragma unroll
    for (int nn = 0; nn < 4; ++nn) {
        const int n = nq * 4 + nn;
        boff[nn] = n * 64 + 8 * (kc ^ (n & 7) ^ ((n >> 3) & 7));
    }
    f32x4 regB[8];

    // A stager: chunk g = i*256 + (tid-256) -> row g>>3, k-slot g&7
    const u16* pa[4];
    if (!isB) {
        #pragma unroll
        for (int i = 0; i < 4; ++i) {
            const int g = i * 256 + (tid - 256);
            const int row = g >> 3, kca = g & 7;
            pa[i] = featb + (size_t)ri[row] * Dn + 8 * (kca ^ (row & 7));
        }
    }

    auto loadB = [&](int ks) {
        const float* p = pw + (size_t)ks * 64 * Dn;
        #pragma unroll
        for (int kk = 0; kk < 8; ++kk) regB[kk] = *(const f32x4*)(p + (size_t)kk * Dn);
    };
    auto writeB = [&](int buf) {
        #pragma unroll
        for (int nn = 0; nn < 4; ++nn) {
            uint4 w = {pk2(regB[0][nn], regB[1][nn]), pk2(regB[2][nn], regB[3][nn]),
                       pk2(regB[4][nn], regB[5][nn]), pk2(regB[6][nn], regB[7][nn])};
            *(uint4*)&Bs[buf][boff[nn]] = w;
        }
    };
    auto loadA = [&](int ks, int buf) {
        #pragma unroll
        for (int i = 0; i < 4; ++i)
            gload_lds16(pa[i] + ks * 64, &As[buf][(i * 256 + (tid - 256)) * 8]);
    };

    f32x4 acc[4][2] = {};
    // prologue: tile0 staged (B via reg round-trip, A via DMA); tile1 loads issued
    if (isB) { loadB(0); writeB(0); loadB(1); }
    else     { loadA(0, 0); }

    for (int ks = 0; ks < 16; ++ks) {
        const int cur = ks & 1;
        // (a) stage tile ks+1 into buf^1; issue tile ks+2 loads
        if (ks < 15) {
            if (isB) { writeB(cur ^ 1); if (ks < 14) loadB(ks + 2); }
            else     { loadA(ks + 1, cur ^ 1); }
        }
        // (b) counted waits + publication barrier (also pins loads above)
        if (isB) {
            asm volatile("s_waitcnt lgkmcnt(0)" ::: "memory");
        } else if (ks < 15) {
            asm volatile("s_waitcnt vmcnt(4)" ::: "memory");
        } else {
            asm volatile("s_waitcnt vmcnt(0)" ::: "memory");
        }
        asm volatile("s_barrier" ::: "memory");

        #pragma unroll
        for (int h = 0; h < 2; ++h) {
            const int kq = h * 4 + (lane >> 4);
            bf16x8 af[4], bfr[2];
            #pragma unroll
            for (int i = 0; i < 4; ++i) {
                int rr = wr * 64 + i * 16 + (lane & 15);
                af[i] = *(const bf16x8*)&As[cur][rr * 64 + 8 * (kq ^ (rr & 7))];
            }
            #pragma unroll
            for (int j = 0; j < 2; ++j) {
                int nn = wc * 32 + j * 16 + (lane & 15);
                bfr[j] = *(const bf16x8*)&Bs[cur][nn * 64 + 8 * (kq ^ (nn & 7) ^ ((nn >> 3) & 7))];
            }
            #pragma unroll
            for (int i = 0; i < 4; ++i)
                #pragma unroll
                for (int j = 0; j < 2; ++j)
                    acc[i][j] = __builtin_amdgcn_mfma_f32_16x16x32_bf16(af[i], bfr[j], acc[i][j], 0, 0, 0);
        }
        // bare barrier: protects buf cur from next iteration's staging
        asm volatile("s_barrier" ::: "memory");
    }

    #pragma unroll
    for (int j = 0; j < 2; ++j) {
        const int n = n0 + wc * 32 + j * 16 + (lane & 15);
        const float bias = b1[t * Dn + n];
        #pragma unroll
        for (int i = 0; i < 4; ++i) {
            #pragma unroll
            for (int r = 0; r < 4; ++r) {
                const int row = wr * 64 + i * 16 + (lane >> 4) * 4 + r;
                if (m0 + row < cnt) {
                    float v = acc[i][j][r] + bias;
                    v = v > 0.f ? v : 0.f;
                    hbuf[(size_t)(t * CAP + m0 + row) * Dn + n] = f2b(v);
                }
            }
        }
    }
}

// ---------------- gemm2 fused-K + epilogue (tanh, std, scatter) --------------
__global__ __launch_bounds__(256, 3) void k_gemm2(
    const u16* __restrict__ hbuf, const float* __restrict__ w2,
    const float* __restrict__ b2, const float* __restrict__ sigma,
    const int* __restrict__ cursor, const int* __restrict__ bucket,
    float* __restrict__ out) {
    __shared__ __align__(16) u16 Asl[32 * 256];   // 16KB [row][k] swizzled
    __shared__ __align__(16) u16 Bsl[64 * 256];   // 32KB [a][k]  swizzled

    const int bid = blockIdx.x;
    const int t = bid & 15, mt = bid >> 4;        // mt 0..15 (32-row tiles)
    int cnt = cursor[t]; if (cnt > CAP) cnt = CAP;
    const int m0 = mt * 32;
    if (m0 >= cnt) return;
    const int tid = threadIdx.x, lane = tid & 63, wv = tid >> 6;
    const int rh = wv & 1, ag = wv >> 1;

    f32x4 acc[2] = {};
    for (int c = 0; c < 4; ++c) {
        const int k0 = c * 256;
        #pragma unroll
        for (int i = 0; i < 4; ++i) {
            int chunk = i * 256 + tid;
            int row = chunk >> 5, cp = chunk & 31;
            int rowg = m0 + row; if (rowg >= cnt) rowg = cnt - 1;
            gload_lds16(hbuf + (size_t)(t * CAP + rowg) * Dn + k0 + 8 * (cp ^ (row & 7)),
                        &Asl[chunk * 8]);
        }
        {
            const int a = tid & 63, kcq = tid >> 6;
            const float* gB = w2 + ((size_t)t * Dn + k0 + kcq * 64) * An + a;
            for (int jb = 0; jb < 8; ++jb) {
                float v[8];
                #pragma unroll
                for (int u = 0; u < 8; ++u) v[u] = gB[(size_t)(jb * 8 + u) * An];
                int k = kcq * 64 + jb * 8;
                uint4 w = {pk2(v[0], v[1]), pk2(v[2], v[3]), pk2(v[4], v[5]), pk2(v[6], v[7])};
                *(uint4*)&Bsl[a * 256 + 8 * ((k >> 3) ^ (a & 7))] = w;
            }
        }
        __syncthreads();
        #pragma unroll
        for (int s = 0; s < 8; ++s) {
            const int r = lane & 15, ch = lane >> 4, cp = s * 4 + ch;
            const int row = rh * 16 + r;
            bf16x8 af = *(const bf16x8*)&Asl[row * 256 + 8 * (cp ^ (row & 7))];
            #pragma unroll
            for (int j = 0; j < 2; ++j) {
                const int a = ag * 32 + j * 16 + r;
                bf16x8 bf = *(const bf16x8*)&Bsl[a * 256 + 8 * (cp ^ (a & 7))];
                acc[j] = __builtin_amdgcn_mfma_f32_16x16x32_bf16(af, bf, acc[j], 0, 0, 0);
            }
        }
        __syncthreads();
    }

    #pragma unroll
    for (int j = 0; j < 2; ++j) {
        const int a = ag * 32 + j * 16 + (lane & 15);
        const float bias = b2[t * An + a];
        const float sd = expf(sigma[t * An + a]);
        #pragma unroll
        for (int r = 0; r < 4; ++r) {
            const int row = m0 + rh * 16 + (lane >> 4) * 4 + r;
            if (row < cnt) {
                const int orig = bucket[t * CAP + row];
                out[(size_t)orig * An + a] = tanhf(acc[j][r] + bias);
                out[(size_t)Bn * An + (size_t)orig * An + a] = sd;
            }
        }
    }
}

// ---------------- launch: 4 nodes, no memset ----------------
extern "C" void kernel_launch(void* const* d_in, const int* in_sizes, int n_in,
                              void* d_out, int out_size, void* d_ws, size_t ws_size,
                              hipStream_t stream) {
    const float* feature = (const float*)d_in[0];
    const float* actor_index = (const float*)d_in[1];
    const float* W1 = (const float*)d_in[2];
    const float* b1 = (const float*)d_in[3];
    const float* W2 = (const float*)d_in[4];
    const float* b2 = (const float*)d_in[5];
    const float* sigma = (const float*)d_in[6];
    float* out = (float*)d_out;
    char* ws = (char*)d_ws;

    if (ws_size < WS_NEED) return;

    int* cursor = (int*)(ws + OFF_CURSOR);
    int* bucket = (int*)(ws + OFF_BUCKET);
    u16* featb  = (u16*)(ws + OFF_FEATB);
    u16* hbuf   = (u16*)(ws + OFF_H);

    k_prep<<<1024, 256, 0, stream>>>(feature, featb, cursor);
    k_scatter<<<Bn / 256, 256, 0, stream>>>(actor_index, cursor, bucket);
    k_gemm1<<<Tn * 8 * 4, 512, 0, stream>>>(featb, W1, b1, bucket, cursor, hbuf);
    k_gemm2<<<Tn * 16, 256, 0, stream>>>(hbuf, W2, b2, sigma, cursor, bucket, out);
}